// Round 7
// baseline (243.740 us; speedup 1.0000x reference)
//
#include <hip/hip_runtime.h>
#include <math.h>

#define NB   128
#define CCH  512
#define HW   784      // 28*28
#define NCLS 1000
#define GRID 256      // one block per CU (2/CU co-residency guaranteed by resources)
#define RNDS 4
#define IMGR 32       // images per round
#define K49  49       // f32x4 per thread per slice (64ch*784/4/256)

typedef float f32x4 __attribute__((ext_vector_type(4)));

// Monotonic-counter grid barrier: each block's thread 0 adds 1, then spins until
// count reaches target = round*GRID. Device-scope atomics (cross-XCD coherent).
__device__ __forceinline__ void grid_barrier(unsigned* bar, unsigned target) {
    __syncthreads();
    if (threadIdx.x == 0) {
        __threadfence();                                   // flush pooled stores
        __hip_atomic_fetch_add(bar, 1u, __ATOMIC_ACQ_REL, __HIP_MEMORY_SCOPE_AGENT);
        while (__hip_atomic_load(bar, __ATOMIC_ACQUIRE, __HIP_MEMORY_SCOPE_AGENT) < target)
            __builtin_amdgcn_s_sleep(2);
    }
    __syncthreads();
}

// Persistent kernel. Block b owns slab q=b&7 (64 channels) of image nl=b>>3 each
// round; feat slice lives in 196 VGPRs -> feat read from HBM exactly once.
// Phase order A,bar,B1,C,B2 keeps rdat dead before B2's register peak.
__global__ __launch_bounds__(256, 2) void k_all(const float* __restrict__ feat,
                                                const int* __restrict__ y,
                                                const float* __restrict__ w,
                                                const float* __restrict__ bias,
                                                float* __restrict__ out,
                                                float* __restrict__ pred,
                                                float* __restrict__ pooled,
                                                unsigned* __restrict__ bar) {
    __shared__ float lds[12544];          // A: per-f32x4 sums; B1/C: red + smask
    float* red   = lds;                   // [5] reduction scratch
    float* smask = lds + 6144;            // [512] own image's full mask

    const int t = threadIdx.x;
    const int lane = t & 63, wv = t >> 6;
    const int b = blockIdx.x;
    const int nl = b >> 3;                // image within round, 0..31
    const int q  = b & 7;                 // 64-channel slab, 0..7

    for (int r = 0; r < RNDS; ++r) {
        const int n = r * IMGR + nl;
        const size_t sbase = ((size_t)n * CCH + (q << 6)) * HW;   // float offset
        const f32x4* src4 = reinterpret_cast<const f32x4*>(feat + sbase);

        // ---- Phase A: slice -> registers; deterministic channel sums ----
        f32x4 rdat[K49];
#pragma unroll
        for (int k = 0; k < K49; ++k) rdat[k] = src4[k * 256 + t];
#pragma unroll
        for (int k = 0; k < K49; ++k) {
            int i = k * 256 + t;
            lds[i] = rdat[k].x + rdat[k].y + rdat[k].z + rdat[k].w;
        }
        __syncthreads();
        {
            // channel c = t>>2 (64 ch/block), part p = t&3: 49 f32x4-sums each
            float s = 0.f;
            int base = (t >> 2) * 196 + (t & 3) * 49;
#pragma unroll
            for (int j = 0; j < K49; ++j) s += lds[base + j];
            s += __shfl_xor(s, 1, 64);
            s += __shfl_xor(s, 2, 64);
            if ((t & 3) == 0)
                pooled[(size_t)n * CCH + (q << 6) + (t >> 2)] = s * (1.0f / 784.0f);
        }
        grid_barrier(bar, (unsigned)(r + 1) * GRID);   // pooled(r) visible grid-wide

        // ---- Phase B1: own image's mask (redundant across its 8 blocks) ----
        {
            int cls = y[n];
            float p0 = pooled[(size_t)n * CCH + t];
            float p1 = pooled[(size_t)n * CCH + t + 256];
            float g0 = w[(size_t)cls * CCH + t] * p0;
            float g1 = w[(size_t)cls * CCH + t + 256] * p1;

            float ss = g0 * g0 + g1 * g1;
#pragma unroll
            for (int o = 32; o; o >>= 1) ss += __shfl_down(ss, o, 64);
            if (lane == 0) red[wv] = ss;
            __syncthreads();
            if (t == 0) red[4] = sqrtf(red[0] + red[1] + red[2] + red[3]);
            __syncthreads();
            float inv = 11.313708498984761f / red[4];   // sqrt(512)/2 / norm
            float v0 = 1.0f + g0 * inv, v1 = 1.0f + g1 * inv;
            __syncthreads();

            float mx = fmaxf(v0, v1);
#pragma unroll
            for (int o = 32; o; o >>= 1) mx = fmaxf(mx, __shfl_down(mx, o, 64));
            if (lane == 0) red[wv] = mx;
            __syncthreads();
            if (t == 0) red[4] = fmaxf(fmaxf(red[0], red[1]), fmaxf(red[2], red[3]));
            __syncthreads();
            float mmax = red[4];
            float e0 = expf(v0 - mmax), e1 = expf(v1 - mmax);
            __syncthreads();

            float se = e0 + e1;
#pragma unroll
            for (int o = 32; o; o >>= 1) se += __shfl_down(se, o, 64);
            if (lane == 0) red[wv] = se;
            __syncthreads();
            if (t == 0) red[4] = red[0] + red[1] + red[2] + red[3];
            __syncthreads();
            float is = 1.0f / red[4];
            smask[t] = e0 * is;
            smask[t + 256] = e1 * is;
            __syncthreads();
        }

        // ---- Phase C: apply mask from registers, stream out (rdat dies here) ----
        {
            f32x4* dst4 = reinterpret_cast<f32x4*>(out + sbase);
            const float* sm = smask + (q << 6);
#pragma unroll
            for (int k = 0; k < K49; ++k) {
                unsigned int i = k * 256u + t;
                float m = sm[i / 196u];
                f32x4 v = rdat[k];
                v.x *= m; v.y *= m; v.z *= m; v.w *= m;
                __builtin_nontemporal_store(v, dst4 + i);
            }
        }

        // ---- Phase B2: pred linear, blocks 0..249, 4 cls each (wave = 1 cls) ----
        if (b < 250) {
            int cls = b * 4 + wv;
            const f32x4* wr4 = reinterpret_cast<const f32x4*>(w + (size_t)cls * CCH);
            f32x4 a0 = wr4[lane * 2], a1 = wr4[lane * 2 + 1];
            float bv = bias[cls];
            for (int nn = 0; nn < IMGR; ++nn) {
                int ni = r * IMGR + nn;
                const f32x4* pr4 = reinterpret_cast<const f32x4*>(pooled + (size_t)ni * CCH);
                f32x4 pp0 = pr4[lane * 2], pp1 = pr4[lane * 2 + 1];
                float s = a0.x * pp0.x + a0.y * pp0.y + a0.z * pp0.z + a0.w * pp0.w
                        + a1.x * pp1.x + a1.y * pp1.y + a1.z * pp1.z + a1.w * pp1.w;
#pragma unroll
                for (int o = 32; o; o >>= 1) s += __shfl_down(s, o, 64);
                if (lane == 0) pred[(size_t)ni * NCLS + cls] = s + bv;
            }
        }
        __syncthreads();   // LDS reuse barrier before next round's Phase A
    }
}

extern "C" void kernel_launch(void* const* d_in, const int* in_sizes, int n_in,
                              void* d_out, int out_size, void* d_ws, size_t ws_size,
                              hipStream_t stream) {
    const float* feat = (const float*)d_in[0];
    const int*   y    = (const int*)d_in[1];
    const float* w    = (const float*)d_in[2];
    const float* b    = (const float*)d_in[3];

    float* out_feat = (float*)d_out;                       // 128*512*784
    float* out_pred = out_feat + (size_t)NB * CCH * HW;    // 128*1000

    float* pooled = (float*)d_ws;                          // 65536 floats
    unsigned* bar = (unsigned*)((char*)d_ws + 65536 * sizeof(float));

    hipMemsetAsync(bar, 0, 64, stream);                    // reset barrier counter
    k_all<<<GRID, 256, 0, stream>>>(feat, y, w, b, out_feat, out_pred, pooled, bar);
}